// Round 7
// baseline (333.871 us; speedup 1.0000x reference)
//
#include <hip/hip_runtime.h>

typedef unsigned short ushort_t;
typedef __attribute__((ext_vector_type(8))) short bs8;       // 8 x bf16 (4 VGPR)
typedef __attribute__((ext_vector_type(4))) float f32x4;
typedef __attribute__((ext_vector_type(4))) unsigned short u16x4;

#define DEV __device__ __forceinline__

DEV unsigned short f2bf(float f){
  unsigned u = __float_as_uint(f);
  u += 0x7fffu + ((u >> 16) & 1u);           // round-to-nearest-even
  return (unsigned short)(u >> 16);
}
DEV float bf2f(unsigned short h){ return __uint_as_float(((unsigned)h) << 16); }

DEV unsigned cvt_pk_bf16(float lo, float hi){
  unsigned r;
  asm volatile("v_cvt_pk_bf16_f32 %0, %1, %2" : "=v"(r) : "v"(lo), "v"(hi));
  return r;
}

DEV void gl2lds16(const void* g, void* l){
  __builtin_amdgcn_global_load_lds((const __attribute__((address_space(1))) void*)g,
                                   (__attribute__((address_space(3))) void*)l, 16, 0, 0);
}

DEV void st_out(ushort_t* C, size_t i, float v){ C[i] = f2bf(v); }
DEV void st_out(float*    C, size_t i, float v){ C[i] = v; }

// ---------------- cast x (fp32 -> bf16), 4 elems/thread ----------------
__global__ __launch_bounds__(256) void cast_x(const float* __restrict__ in,
                                              ushort_t* __restrict__ outb){
  size_t i = ((size_t)blockIdx.x * 256 + threadIdx.x) * 4;
  float4 v = *(const float4*)(in + i);
  u16x4 o;
  o[0] = f2bf(v.x); o[1] = f2bf(v.y); o[2] = f2bf(v.z); o[3] = f2bf(v.w);
  *(u16x4*)(outb + i) = o;
}

// ---------------- ALL weight transpose-casts in one dispatch ----------------
// groups (K,N,blocks): dq(2048,1024,2048) dkv(2048,512,1024) kr(2048,1024,2048)
// uq(1024,2048,2048) qr(1024,1024,1024) uk(512,2048,1024) uv(512,2048,1024) o(2048,2048,4096)
__global__ __launch_bounds__(256) void tcast_all(
    const float* __restrict__ s0, const float* __restrict__ s1,
    const float* __restrict__ s2, const float* __restrict__ s3,
    const float* __restrict__ s4, const float* __restrict__ s5,
    const float* __restrict__ s6, const float* __restrict__ s7,
    ushort_t* __restrict__ d0, ushort_t* __restrict__ d1,
    ushort_t* __restrict__ d2, ushort_t* __restrict__ d3,
    ushort_t* __restrict__ d4, ushort_t* __restrict__ d5,
    ushort_t* __restrict__ d6, ushort_t* __restrict__ d7){
  __shared__ float tile[32][33];
  const int bid = blockIdx.x;
  const float* src; ushort_t* dst; int K, N, loc;
  if      (bid <  2048){ src=s0; dst=d0; K=2048; N=1024; loc=bid; }
  else if (bid <  3072){ src=s1; dst=d1; K=2048; N=512;  loc=bid-2048; }
  else if (bid <  5120){ src=s2; dst=d2; K=2048; N=1024; loc=bid-3072; }
  else if (bid <  7168){ src=s3; dst=d3; K=1024; N=2048; loc=bid-5120; }
  else if (bid <  8192){ src=s4; dst=d4; K=1024; N=1024; loc=bid-7168; }
  else if (bid <  9216){ src=s5; dst=d5; K=512;  N=2048; loc=bid-8192; }
  else if (bid < 10240){ src=s6; dst=d6; K=512;  N=2048; loc=bid-9216; }
  else                 { src=s7; dst=d7; K=2048; N=2048; loc=bid-10240; }
  const int nx = N >> 5;
  const int n0 = (loc % nx) << 5, k0 = (loc / nx) << 5;
  const int tx = threadIdx.x & 31, ty = threadIdx.x >> 5;
  for (int r = ty; r < 32; r += 8)
    tile[r][tx] = src[(size_t)(k0 + r) * N + n0 + tx];
  __syncthreads();
  for (int r = ty; r < 32; r += 8)
    dst[(size_t)(n0 + r) * K + k0 + tx] = f2bf(tile[tx][r]);
}

// ---------------- bf16 transpose per (b,h): v[M][ldv] -> vT[BH][128][T] ----------------
__global__ __launch_bounds__(256) void transpose_v(const ushort_t* __restrict__ v, int ldv,
                                                   ushort_t* __restrict__ vT){
  __shared__ ushort_t tile[32][33];
  int bh = blockIdx.z; int b = bh >> 4, h = bh & 15;
  int t0 = blockIdx.x * 32, d0 = blockIdx.y * 32;
  int tx = threadIdx.x, ty = threadIdx.y;
  for (int r = ty; r < 32; r += 8)
    tile[r][tx] = v[((size_t)(b * 2048 + t0 + r)) * ldv + h * 128 + d0 + tx];
  __syncthreads();
  for (int r = ty; r < 32; r += 8)
    vT[((size_t)bh * 128 + d0 + r) * 2048 + t0 + tx] = tile[tx][r];
}

// ================= 256x256 8-phase GEMM core (T2+T3+T4+T5), BK=64 =================
DEV void gemm_core(const ushort_t* __restrict__ A, int lda,
                   const ushort_t* __restrict__ BT, int K,
                   int m0, int n0, ushort_t* lds, f32x4 (&acc)[8][4]){
  const int tid = threadIdx.x, lane = tid & 63, wid = tid >> 6;
  const int l15 = lane & 15, lhi = lane >> 4;
  const int wr = wid >> 2, wc = wid & 3;

  const int trow = tid >> 3;
  const int tcsrc = (tid & 7) ^ (trow & 7);
  const ushort_t* gA[2][2];
  const ushort_t* gB[2][2];
#pragma unroll
  for (int h = 0; h < 2; ++h)
#pragma unroll
    for (int i = 0; i < 2; ++i){
      gA[h][i] = A  + (size_t)(m0 + h * 128 + i * 64 + trow) * lda + tcsrc * 8;
      gB[h][i] = BT + (size_t)(n0 + h * 128 + i * 64 + trow) * K   + tcsrc * 8;
    }

  auto STAGE_A = [&](int buf, int h, int kt){
    gl2lds16(gA[h][0] + (size_t)kt * 64, lds + buf * 32768 + h * 8192 + tid * 8);
    gl2lds16(gA[h][1] + (size_t)kt * 64, lds + buf * 32768 + h * 8192 + 4096 + tid * 8);
  };
  auto STAGE_B = [&](int buf, int h, int kt){
    gl2lds16(gB[h][0] + (size_t)kt * 64, lds + buf * 32768 + 16384 + h * 8192 + tid * 8);
    gl2lds16(gB[h][1] + (size_t)kt * 64, lds + buf * 32768 + 16384 + h * 8192 + 4096 + tid * 8);
  };

  const int ck0 = ((lhi) ^ (l15 & 7)) << 3;
  const int ck1 = ((4 + lhi) ^ (l15 & 7)) << 3;

  bs8 aF[4][2], bLo[2][2], bHi[2][2];

  auto RDA = [&](int buf, int mq){
#pragma unroll
    for (int m = 0; m < 4; ++m){
      const ushort_t* r = lds + buf * 32768 + wr * 8192 + ((mq + m) * 16 + l15) * 64;
      aF[m][0] = *(const bs8*)(r + ck0);
      aF[m][1] = *(const bs8*)(r + ck1);
    }
  };
  auto RDB = [&](int buf, int nq, bs8 (&br)[2][2]){
#pragma unroll
    for (int n = 0; n < 2; ++n){
      const ushort_t* r = lds + buf * 32768 + 16384 + (wc >> 1) * 8192 +
                          ((wc & 1) * 64 + (nq + n) * 16 + l15) * 64;
      br[n][0] = *(const bs8*)(r + ck0);
      br[n][1] = *(const bs8*)(r + ck1);
    }
  };
  auto MMA = [&](int mq, int nq, bs8 (&br)[2][2]){
    __builtin_amdgcn_s_setprio(1);
#pragma unroll
    for (int m = 0; m < 4; ++m)
#pragma unroll
      for (int n = 0; n < 2; ++n){
        acc[mq + m][nq + n] = __builtin_amdgcn_mfma_f32_16x16x32_bf16(aF[m][0], br[n][0], acc[mq + m][nq + n], 0, 0, 0);
        acc[mq + m][nq + n] = __builtin_amdgcn_mfma_f32_16x16x32_bf16(aF[m][1], br[n][1], acc[mq + m][nq + n], 0, 0, 0);
      }
    __builtin_amdgcn_s_setprio(0);
  };

#define BAR() __builtin_amdgcn_s_barrier()
#define LGK() asm volatile("s_waitcnt lgkmcnt(0)" ::: "memory")
#define VMC4() asm volatile("s_waitcnt vmcnt(4)" ::: "memory")

  const int nkt = K >> 6;
  const int nIter = K >> 7;

  STAGE_A(0, 0, 0); STAGE_A(0, 1, 0); STAGE_B(0, 0, 0); STAGE_B(0, 1, 0);
  STAGE_B(1, 0, 1); STAGE_B(1, 1, 1);
  VMC4();
  BAR();

  for (int it = 0; it < nIter; ++it){
    const int kt1 = 2 * it + 1;
    int kt2 = 2 * it + 2; if (kt2 > nkt - 1) kt2 = nkt - 1;
    int kt3 = 2 * it + 3; if (kt3 > nkt - 1) kt3 = nkt - 1;
    RDA(0, 0); RDB(0, 0, bLo);
    STAGE_A(1, 0, kt1);
    BAR(); LGK(); MMA(0, 0, bLo); BAR();
    RDB(0, 2, bHi);
    STAGE_A(1, 1, kt1);
    BAR(); LGK(); MMA(0, 2, bHi); BAR();
    RDA(0, 4);
    STAGE_B(0, 0, kt2);
    BAR(); LGK(); MMA(4, 0, bLo); BAR();
    STAGE_B(0, 1, kt2);
    BAR(); LGK(); MMA(4, 2, bHi);
    VMC4(); BAR();
    RDA(1, 0); RDB(1, 0, bLo);
    STAGE_A(0, 0, kt2);
    BAR(); LGK(); MMA(0, 0, bLo); BAR();
    RDB(1, 2, bHi);
    STAGE_A(0, 1, kt2);
    BAR(); LGK(); MMA(0, 2, bHi); BAR();
    RDA(1, 4);
    STAGE_B(1, 0, kt3);
    BAR(); LGK(); MMA(4, 0, bLo); BAR();
    STAGE_B(1, 1, kt3);
    BAR(); LGK(); MMA(4, 2, bHi);
    VMC4(); BAR();
  }
#undef BAR
#undef LGK
#undef VMC4
}

// EPI 0: plain C[M][N]. EPI 1: comb1[4096][1536] + rope(kr)->Ka.
// EPI 2: Qa (qc + rope(qr)), pre-scaled. EPI 3: Ka(kc) + vb(C).
template<int EPI, typename OT>
DEV void gemm_epi(f32x4 (&acc)[8][4], OT* __restrict__ C, int N, int m0, int n0,
                  ushort_t* __restrict__ aux,
                  const float* __restrict__ fcp, const float* __restrict__ fsp){
  const int tid = threadIdx.x, lane = tid & 63, wid = tid >> 6;
  const int l15 = lane & 15, lhi = lane >> 4;
  const int wr = wid >> 2, wc = wid & 3;
  const float SC = (EPI == 2) ? (0.07216878364870323f * 1.4426950408889634f) : 1.0f;
  const int RBASE = (EPI == 1) ? 1536 : 2048;
#pragma unroll
  for (int m = 0; m < 8; ++m){
    const int r = m0 + wr * 128 + m * 16 + lhi * 4;
#pragma unroll
    for (int n = 0; n < 4; ++n){
      const int c = n0 + wc * 64 + n * 16 + l15;
      if (EPI == 0){
#pragma unroll
        for (int j = 0; j < 4; ++j)
          st_out(C, (size_t)(r + j) * N + c, acc[m][n][j]);
      } else if ((EPI == 1 && c < 1536)){
#pragma unroll
        for (int j = 0; j < 4; ++j)
          C[(size_t)(r + j) * 1536 + c] = (OT)f2bf(acc[m][n][j]);
      } else if (EPI == 2 && c < 2048){
        int hh = c >> 7, d = c & 127;
#pragma unroll
        for (int j = 0; j < 4; ++j){
          int rr = r + j, bb = rr >> 11, tt = rr & 2047;
          aux[((size_t)(bb * 16 + hh) * 2048 + tt) * 192 + d] = f2bf(acc[m][n][j] * SC);
        }
      } else if (EPI == 3 && c < 2048){
        int hh = c >> 7, d = c & 127;
#pragma unroll
        for (int j = 0; j < 4; ++j){
          int rr = r + j, bb = rr >> 11, tt = rr & 2047;
          aux[((size_t)(bb * 16 + hh) * 2048 + tt) * 192 + d] = f2bf(acc[m][n][j]);
        }
      } else if (EPI == 3){
#pragma unroll
        for (int j = 0; j < 4; ++j)
          C[(size_t)(r + j) * 2048 + (c - 2048)] = (OT)f2bf(acc[m][n][j]);
      } else {
        int cr = c - RBASE;
        int hh = cr >> 6, dr = cr & 63, ii = dr >> 1;
#pragma unroll
        for (int j = 0; j < 4; ++j){
          int rr = r + j, bb = rr >> 11, tt = rr & 2047;
          float v = acc[m][n][j] * SC;
          float pv = __shfl_xor(v, 1);
          float co = fcp[tt * 32 + ii], si = fsp[tt * 32 + ii];
          float o = (l15 & 1) ? fmaf(pv, si, v * co) : fmaf(-pv, si, v * co);
          aux[((size_t)(bb * 16 + hh) * 2048 + tt) * 192 + 128 + dr] = f2bf(o);
        }
      }
    }
  }
}

template<int EPI, typename OT>
__global__ __launch_bounds__(512, 2) void gemm256(const ushort_t* __restrict__ A, int lda,
                                                  const ushort_t* __restrict__ BT,
                                                  OT* __restrict__ C,
                                                  int M, int N, int K,
                                                  ushort_t* __restrict__ aux,
                                                  const float* __restrict__ fcp,
                                                  const float* __restrict__ fsp){
  __shared__ __align__(16) ushort_t lds[65536];
  const int nbx = M >> 8;
  const int nwg = gridDim.x;
  const int orig = blockIdx.x;
  const int wg = (orig & 7) * (nwg >> 3) + (orig >> 3);
  const int m0 = (wg % nbx) << 8;
  const int n0 = (wg / nbx) << 8;
  f32x4 acc[8][4] = {};
  gemm_core(A, lda, BT, K, m0, n0, lds, acc);
  gemm_epi<EPI, OT>(acc, C, N, m0, n0, aux, fcp, fsp);
}

// GEMM2 (192 blocks) + GEMM3 (256 blocks) fused: 448 blocks, both depend only on comb1.
__global__ __launch_bounds__(512, 2) void gemm23(const ushort_t* __restrict__ A2,
                                                 const ushort_t* __restrict__ BT2,
                                                 const ushort_t* __restrict__ A3,
                                                 const ushort_t* __restrict__ BT3,
                                                 ushort_t* __restrict__ vb,
                                                 ushort_t* __restrict__ Qa,
                                                 ushort_t* __restrict__ Ka,
                                                 const float* __restrict__ fcp,
                                                 const float* __restrict__ fsp){
  __shared__ __align__(16) ushort_t lds[65536];
  const int nwg = gridDim.x;   // 448
  const int orig = blockIdx.x;
  const int wg = (orig & 7) * (nwg >> 3) + (orig >> 3);
  f32x4 acc[8][4] = {};
  if (wg < 192){
    const int m0 = (wg % 16) << 8, n0 = (wg / 16) << 8;
    gemm_core(A2, 1536, BT2, 1024, m0, n0, lds, acc);
    gemm_epi<2, ushort_t>(acc, nullptr, 3072, m0, n0, Qa, fcp, fsp);
  } else {
    const int g = wg - 192;
    const int m0 = (g % 16) << 8, n0 = (g / 16) << 8;
    gemm_core(A3, 1536, BT3, 512, m0, n0, lds, acc);
    gemm_epi<3, ushort_t>(acc, vb, 4096, m0, n0, Ka, fcp, fsp);
  }
}

// ====== flash attention v6: parity-split waves (halved LDS traffic) ======
// 8 waves = 4 q-subtiles(32q) x 2 kv-parities. grid (32 bh, 8 p); block does
// qb0=15-p then qb1=p (34 uniform tile-units). Segment-end LSE merge via LDS.
__global__ __launch_bounds__(512, 1) void attn_kernel(const ushort_t* __restrict__ Qa,
                                                      const ushort_t* __restrict__ Ka,
                                                      const ushort_t* __restrict__ VT,
                                                      ushort_t* __restrict__ O){
  // staging [K0 12288 | K1 12288 | V0 8192 | V1 8192] = 80KB; merge region 68KB
  __shared__ __align__(16) ushort_t lds[40960 + 34816];
  float* fm = (float*)(lds + 40960);
  const int tid = threadIdx.x, lane = tid & 63, wid = tid >> 6;
  const int sw = wid & 3, par = wid >> 2;
  const int bh = blockIdx.x, p = blockIdx.y;
  const int b = bh >> 4, h = bh & 15;
  const int qb0 = 15 - p, qb1 = p;
  const int nkt0 = 2 * qb0 + 2;
  const int NT = 34;
  const int l15 = lane & 15, lhi = lane >> 4;

  const ushort_t* Kbh = Ka + (size_t)bh * 2048 * 192;
  const ushort_t* Vbh = VT + (size_t)bh * 128 * 2048;

  // staging sources (inverse-swizzled global addresses, rule #21); 512-thread split
  const ushort_t* ksrc[3];
#pragma unroll
  for (int i = 0; i < 3; ++i){
    int c = i * 512 + tid;
    int row = c / 24, col = c % 24;
    int hk = (row & 3) | (((row >> 3) & 1) << 2);
    ksrc[i] = Kbh + (size_t)row * 192 + (col ^ hk) * 8;
  }
  const ushort_t* vsrc[2];
#pragma unroll
  for (int i = 0; i < 2; ++i){
    int c = i * 512 + tid;
    int d = c >> 3, col = c & 7;
    vsrc[i] = Vbh + (size_t)d * 2048 + (col ^ (d & 7)) * 8;
  }

  auto STAGE = [&](int ft, int buf){
    int kt = (ft < nkt0) ? ft : ft - nkt0;
#pragma unroll
    for (int i = 0; i < 3; ++i)
      gl2lds16(ksrc[i] + (size_t)kt * 12288, lds + buf * 12288 + (i * 512 + tid) * 8);
#pragma unroll
    for (int i = 0; i < 2; ++i)
      gl2lds16(vsrc[i] + kt * 64, lds + 24576 + buf * 8192 + (i * 512 + tid) * 8);
  };

  bs8 qf[2][6];
  auto LOADQ = [&](int qb){
#pragma unroll
    for (int qg = 0; qg < 2; ++qg){
      const size_t qrow = ((size_t)bh * 2048 + qb * 128 + sw * 32 + qg * 16 + l15) * 192;
#pragma unroll
      for (int kc = 0; kc < 6; ++kc)
        qf[qg][kc] = *(const bs8*)(Qa + qrow + kc * 32 + lhi * 8);
    }
  };

  f32x4 acc[2][8] = {};
  float mrow[2] = {-1e30f, -1e30f};
  float lrow[2] = {0.f, 0.f};

  // segment-end merge: odd parity publishes (m,l,acc); even merges + writes O
  auto MERGE_EPI = [&](int qb){
    if (par == 1){
#pragma unroll
      for (int qg = 0; qg < 2; ++qg)
#pragma unroll
        for (int f = 0; f < 8; ++f)
          *(f32x4*)(fm + sw * 4096 + (qg * 8 + f) * 256 + lane * 4) = acc[qg][f];
      f32x4 ml;
      ml[0] = mrow[0]; ml[1] = lrow[0]; ml[2] = mrow[1]; ml[3] = lrow[1];
      *(f32x4*)(fm + 16384 + sw * 256 + lane * 4) = ml;
    }
    __syncthreads();
    if (par == 0){
      f32x4 ml = *(const f32x4*)(fm + 16384 + sw * 256 + lane * 4);
#pragma unroll
      for (int qg = 0; qg < 2; ++qg){
        float m1 = ml[2 * qg], l1 = ml[2 * qg + 1];
        float mm = fmaxf(mrow[qg], m1);
        float f0 = exp2f(mrow[qg] - mm), f1v = exp2f(m1 - mm);
        float rl = 1.0f / (lrow[qg] * f0 + l1 * f1v);
        int t = qb * 128 + sw * 32 + qg * 16 + l15;
#pragma unroll
        for (int f = 0; f < 8; ++f){
          f32x4 a1 = *(const f32x4*)(fm + sw * 4096 + (qg * 8 + f) * 256 + lane * 4);
          u16x4 o;
#pragma unroll
          for (int j = 0; j < 4; ++j)
            o[j] = f2bf((acc[qg][f][j] * f0 + a1[j] * f1v) * rl);
          *(u16x4*)(O + ((size_t)b * 2048 + t) * 2048 + h * 128 + f * 16 + lhi * 4) = o;
        }
      }
    }
  };

  const int hkr = (l15 & 3) | (((l15 >> 2) & 1) << 2);

#define BARR() __builtin_amdgcn_s_barrier()
#define LGK0() asm volatile("s_waitcnt lgkmcnt(0)" ::: "memory")
#define VMC(n) asm volatile("s_waitcnt vmcnt(" #n ")" ::: "memory")

  LOADQ(qb0);
  STAGE(0, 0);
  STAGE(1, 1);
  VMC(5);
  BARR();

  for (int ft = 0; ft < NT; ++ft){
    if (ft == nkt0){
      MERGE_EPI(qb0);
#pragma unroll
      for (int qg = 0; qg < 2; ++qg)
#pragma unroll
        for (int f = 0; f < 8; ++f) acc[qg][f] = (f32x4){0.f, 0.f, 0.f, 0.f};
      mrow[0] = mrow[1] = -1e30f; lrow[0] = lrow[1] = 0.f;
      LOADQ(qb1);
    }
    const int seg = (ft >= nkt0) ? 1 : 0;
    const int kt = seg ? ft - nkt0 : ft;
    const int qb = seg ? qb1 : qb0;
    const int qm0 = qb << 7;
    const int mylast = 2 * qb + (sw >> 1);
    const int cur = ft & 1;
    const ushort_t* Kb = lds + cur * 12288;
    const ushort_t* Vb = lds + 24576 + cur * 8192;

    if (((kt & 1) == par) && kt <= mylast){
      // S^T = K x Q^T (permuted kv->A-row mapping)
      f32x4 s[2][4] = {};
      __builtin_amdgcn_s_setprio(1);
#pragma unroll
      for (int kc = 0; kc < 6; ++kc){
        bs8 kf4[4];
#pragma unroll
        for (int m = 0; m < 4; ++m){
          int row = ((m >> 1) << 5) + ((l15 >> 2) << 3) + ((m & 1) << 2) + (l15 & 3);
          kf4[m] = *(const bs8*)(Kb + row * 192 + (((kc * 4 + lhi) ^ hkr) << 3));
        }
#pragma unroll
        for (int qg = 0; qg < 2; ++qg)
#pragma unroll
          for (int m = 0; m < 4; ++m)
            s[qg][m] = __builtin_amdgcn_mfma_f32_16x16x32_bf16(kf4[m], qf[qg][kc], s[qg][m], 0, 0, 0);
      }
      __builtin_amdgcn_s_setprio(0);

      const bool noMask = (kt * 64 + 63) <= (qm0 + sw * 32);
      bs8 pb[2][2];
#pragma unroll
      for (int qg = 0; qg < 2; ++qg){
        const int qi = qm0 + sw * 32 + qg * 16 + l15;
        float rmax = -3e38f;
#pragma unroll
        for (int m = 0; m < 4; ++m)
#pragma unroll
          for (int j = 0; j < 4; ++j){
            float sv = s[qg][m][j];
            if (!noMask){
              int ki = kt * 64 + ((m >> 1) << 5) + (lhi << 3) + ((m & 1) << 2) + j;
              if (ki > qi) sv = -3e38f;
            }
            s[qg][m][j] = sv;
            rmax = fmaxf(rmax, sv);
          }
        rmax = fmaxf(rmax, __shfl_xor(rmax, 16));
        rmax = fmaxf(rmax, __shfl_xor(rmax, 32));
        if (!__all(rmax <= mrow[qg] + 8.f)){
          float mnew = fmaxf(mrow[qg], rmax);
          float osc = exp2f(mrow[qg] - mnew);
          lrow[qg] *= osc;
#pragma unroll
          for (int f = 0; f < 8; ++f) acc[qg][f] *= osc;
          mrow[qg] = mnew;
        }
        float rsum = 0.f;
#pragma unroll
        for (int m = 0; m < 4; ++m)
#pragma unroll
          for (int j = 0; j < 4; ++j){
            float pv = exp2f(s[qg][m][j] - mrow[qg]);
            s[qg][m][j] = pv;
            rsum += pv;
          }
        rsum += __shfl_xor(rsum, 16);
        rsum += __shfl_xor(rsum, 32);
        lrow[qg] += rsum;

        // pack P via v_cvt_pk_bf16_f32 (T12)
#pragma unroll
        for (int kc2 = 0; kc2 < 2; ++kc2){
          union { bs8 v; unsigned u[4]; } pu;
#pragma unroll
          for (int half = 0; half < 2; ++half){
            const f32x4& sv = s[qg][2 * kc2 + half];
            pu.u[2 * half]     = cvt_pk_bf16(sv[0], sv[1]);
            pu.u[2 * half + 1] = cvt_pk_bf16(sv[2], sv[3]);
          }
          pb[qg][kc2] = pu.v;
        }
      }

      // O^T += V^T x P^T
      __builtin_amdgcn_s_setprio(1);
#pragma unroll
      for (int kc2 = 0; kc2 < 2; ++kc2)
#pragma unroll
        for (int f = 0; f < 8; ++f){
          bs8 vf = *(const bs8*)(Vb + (f * 16 + l15) * 64 + (((kc2 * 4 + lhi) ^ (l15 & 7)) << 3));
#pragma unroll
          for (int qg = 0; qg < 2; ++qg)
            acc[qg][f] = __builtin_amdgcn_mfma_f32_16x16x32_bf16(vf, pb[qg][kc2], acc[qg][f], 0, 0, 0);
        }
      __builtin_amdgcn_s_setprio(0);
    }

    LGK0();
    BARR();
    if (ft + 2 < NT){
      STAGE(ft + 2, cur);
      VMC(5);
    } else {
      VMC(0);
    }
    BARR();
  }
#undef BARR
#undef LGK0
#undef VMC

  MERGE_EPI(qb1);
}

extern "C" void kernel_launch(void* const* d_in, const int* in_sizes, int n_in,
                              void* d_out, int out_size, void* d_ws, size_t ws_size,
                              hipStream_t stream){
  constexpr int Bc = 2, Tc = 2048, Cc = 2048, Hc = 16, HDc = 128, RDc = 64, KVRc = 512, QRc = 1024;
  constexpr int Mx = Bc * Tc; // 4096
  const float* x     = (const float*)d_in[0];
  const float* w_dq  = (const float*)d_in[1];
  const float* w_uq  = (const float*)d_in[2];
  const float* w_dkv = (const float*)d_in[3];
  const float* w_uk  = (const float*)d_in[4];
  const float* w_uv  = (const float*)d_in[5];
  const float* w_qr  = (const float*)d_in[6];
  const float* w_kr  = (const float*)d_in[7];
  const float* w_o   = (const float*)d_in[8];
  const float* fc    = (const float*)d_in[9];
  const float* fs    = (const float*)d_in[10];
  float* out = (float*)d_out;

  char* ws = (char*)d_ws;
  size_t off = 0;
  auto alloc = [&](size_t elems) -> ushort_t* {
    ushort_t* p = (ushort_t*)(ws + off);
    off += ((elems * 2) + 255) & ~(size_t)255;
    return p;
  };
  ushort_t* xb    = alloc((size_t)Mx * Cc);
  // GEMM1 BT group (adjacent): [wdq 1024 | wdkv 512 | wkr 1024] rows, K=2048
  ushort_t* wdqT  = alloc((size_t)QRc * Cc);
  ushort_t* wdkvT = alloc((size_t)KVRc * Cc);
  ushort_t* wkrT  = alloc((size_t)(Hc * RDc) * Cc);
  // GEMM2 BT group: [wuq 2048 | wqr 1024] rows, K=1024
  ushort_t* wuqT  = alloc((size_t)(Hc * HDc) * QRc);
  ushort_t* wqrT  = alloc((size_t)(Hc * RDc) * QRc);
  // GEMM3 BT group: [wuk 2048 | wuv 2048] rows, K=512
  ushort_t* wukT  = alloc((size_t)(Hc * HDc) * KVRc);
  ushort_t* wuvT  = alloc((size_t)(Hc * HDc) * KVRc);
  ushort_t* woT   = alloc((size_t)Cc * (Hc * HDc));
  ushort_t* comb1 = alloc((size_t)Mx * 1536);   // [cq 1024 | ckv 512]
  ushort_t* vb    = alloc((size_t)Mx * 2048);   // v (pre-transpose)
  ushort_t* Qa    = alloc((size_t)Bc * Hc * Tc * 192);
  ushort_t* Ka    = alloc((size_t)Bc * Hc * Tc * 192);
  ushort_t* vT    = alloc((size_t)Bc * Hc * HDc * Tc);
  ushort_t* O     = xb;  // alias: xb dead after GEMM1

  cast_x<<<dim3(((size_t)Mx * Cc) / 1024), 256, 0, stream>>>(x, xb);

  tcast_all<<<dim3(14336), 256, 0, stream>>>(w_dq, w_dkv, w_kr, w_uq, w_qr, w_uk, w_uv, w_o,
                                             wdqT, wdkvT, wkrT, wuqT, wqrT, wukT, wuvT, woT);

  // GEMM1: x @ [w_dq|w_dkv|w_kr] -> comb1[.][1536] + rope(kr)->Ka[..][128..192)
  gemm256<1, ushort_t><<<dim3((Mx / 256) * (2560 / 256)), 512, 0, stream>>>(
      xb, Cc, wdqT, comb1, Mx, 2560, Cc, Ka, fc, fs);
  // GEMM2+3 fused: cq @ [w_uq|w_qr] -> Qa ; ckv @ [w_uk|w_uv] -> Ka(kc) + vb
  gemm23<<<dim3(448), 512, 0, stream>>>(comb1, wuqT, comb1 + QRc, wukT, vb, Qa, Ka, fc, fs);

  transpose_v<<<dim3(Tc / 32, HDc / 32, Bc * Hc), dim3(32, 8), 0, stream>>>(vb, 2048, vT);

  attn_kernel<<<dim3(Bc * Hc, 8), 512, 0, stream>>>(Qa, Ka, vT, O);

  // GEMM4: O @ w_o -> out [4096][2048] fp32
  gemm256<0, float><<<dim3((Mx / 256) * (Cc / 256)), 512, 0, stream>>>(
      O, Hc * HDc, woT, out, Mx, Cc, Hc * HDc, nullptr, nullptr, nullptr);
}

// Round 8
// 306.514 us; speedup vs baseline: 1.0893x; 1.0893x over previous
//
#include <hip/hip_runtime.h>

typedef unsigned short ushort_t;
typedef __attribute__((ext_vector_type(8))) short bs8;       // 8 x bf16 (4 VGPR)
typedef __attribute__((ext_vector_type(4))) float f32x4;
typedef __attribute__((ext_vector_type(4))) unsigned short u16x4;

#define DEV __device__ __forceinline__

DEV unsigned short f2bf(float f){
  unsigned u = __float_as_uint(f);
  u += 0x7fffu + ((u >> 16) & 1u);           // round-to-nearest-even
  return (unsigned short)(u >> 16);
}
DEV float bf2f(unsigned short h){ return __uint_as_float(((unsigned)h) << 16); }

DEV unsigned cvt_pk_bf16(float lo, float hi){
  unsigned r;
  asm volatile("v_cvt_pk_bf16_f32 %0, %1, %2" : "=v"(r) : "v"(lo), "v"(hi));
  return r;
}

DEV void gl2lds16(const void* g, void* l){
  __builtin_amdgcn_global_load_lds((const __attribute__((address_space(1))) void*)g,
                                   (__attribute__((address_space(3))) void*)l, 16, 0, 0);
}

DEV void st_out(ushort_t* C, size_t i, float v){ C[i] = f2bf(v); }
DEV void st_out(float*    C, size_t i, float v){ C[i] = v; }

// ---------------- cast x (fp32 -> bf16), 4 elems/thread ----------------
__global__ __launch_bounds__(256) void cast_x(const float* __restrict__ in,
                                              ushort_t* __restrict__ outb){
  size_t i = ((size_t)blockIdx.x * 256 + threadIdx.x) * 4;
  float4 v = *(const float4*)(in + i);
  u16x4 o;
  o[0] = f2bf(v.x); o[1] = f2bf(v.y); o[2] = f2bf(v.z); o[3] = f2bf(v.w);
  *(u16x4*)(outb + i) = o;
}

// ---------------- ALL weight transpose-casts in one dispatch ----------------
__global__ __launch_bounds__(256) void tcast_all(
    const float* __restrict__ s0, const float* __restrict__ s1,
    const float* __restrict__ s2, const float* __restrict__ s3,
    const float* __restrict__ s4, const float* __restrict__ s5,
    const float* __restrict__ s6, const float* __restrict__ s7,
    ushort_t* __restrict__ d0, ushort_t* __restrict__ d1,
    ushort_t* __restrict__ d2, ushort_t* __restrict__ d3,
    ushort_t* __restrict__ d4, ushort_t* __restrict__ d5,
    ushort_t* __restrict__ d6, ushort_t* __restrict__ d7){
  __shared__ float tile[32][33];
  const int bid = blockIdx.x;
  const float* src; ushort_t* dst; int K, N, loc;
  if      (bid <  2048){ src=s0; dst=d0; K=2048; N=1024; loc=bid; }
  else if (bid <  3072){ src=s1; dst=d1; K=2048; N=512;  loc=bid-2048; }
  else if (bid <  5120){ src=s2; dst=d2; K=2048; N=1024; loc=bid-3072; }
  else if (bid <  7168){ src=s3; dst=d3; K=1024; N=2048; loc=bid-5120; }
  else if (bid <  8192){ src=s4; dst=d4; K=1024; N=1024; loc=bid-7168; }
  else if (bid <  9216){ src=s5; dst=d5; K=512;  N=2048; loc=bid-8192; }
  else if (bid < 10240){ src=s6; dst=d6; K=512;  N=2048; loc=bid-9216; }
  else                 { src=s7; dst=d7; K=2048; N=2048; loc=bid-10240; }
  const int nx = N >> 5;
  const int n0 = (loc % nx) << 5, k0 = (loc / nx) << 5;
  const int tx = threadIdx.x & 31, ty = threadIdx.x >> 5;
  for (int r = ty; r < 32; r += 8)
    tile[r][tx] = src[(size_t)(k0 + r) * N + n0 + tx];
  __syncthreads();
  for (int r = ty; r < 32; r += 8)
    dst[(size_t)(n0 + r) * K + k0 + tx] = f2bf(tile[tx][r]);
}

// ---------------- bf16 transpose per (b,h): v[M][ldv] -> vT[BH][128][T] ----------------
__global__ __launch_bounds__(256) void transpose_v(const ushort_t* __restrict__ v, int ldv,
                                                   ushort_t* __restrict__ vT){
  __shared__ ushort_t tile[32][33];
  int bh = blockIdx.z; int b = bh >> 4, h = bh & 15;
  int t0 = blockIdx.x * 32, d0 = blockIdx.y * 32;
  int tx = threadIdx.x, ty = threadIdx.y;
  for (int r = ty; r < 32; r += 8)
    tile[r][tx] = v[((size_t)(b * 2048 + t0 + r)) * ldv + h * 128 + d0 + tx];
  __syncthreads();
  for (int r = ty; r < 32; r += 8)
    vT[((size_t)bh * 128 + d0 + r) * 2048 + t0 + tx] = tile[tx][r];
}

// ================= 256x256 8-phase GEMM core (T2+T3+T4+T5), BK=64 =================
DEV void gemm_core(const ushort_t* __restrict__ A, int lda,
                   const ushort_t* __restrict__ BT, int K,
                   int m0, int n0, ushort_t* lds, f32x4 (&acc)[8][4]){
  const int tid = threadIdx.x, lane = tid & 63, wid = tid >> 6;
  const int l15 = lane & 15, lhi = lane >> 4;
  const int wr = wid >> 2, wc = wid & 3;

  const int trow = tid >> 3;
  const int tcsrc = (tid & 7) ^ (trow & 7);
  const ushort_t* gA[2][2];
  const ushort_t* gB[2][2];
#pragma unroll
  for (int h = 0; h < 2; ++h)
#pragma unroll
    for (int i = 0; i < 2; ++i){
      gA[h][i] = A  + (size_t)(m0 + h * 128 + i * 64 + trow) * lda + tcsrc * 8;
      gB[h][i] = BT + (size_t)(n0 + h * 128 + i * 64 + trow) * K   + tcsrc * 8;
    }

  auto STAGE_A = [&](int buf, int h, int kt){
    gl2lds16(gA[h][0] + (size_t)kt * 64, lds + buf * 32768 + h * 8192 + tid * 8);
    gl2lds16(gA[h][1] + (size_t)kt * 64, lds + buf * 32768 + h * 8192 + 4096 + tid * 8);
  };
  auto STAGE_B = [&](int buf, int h, int kt){
    gl2lds16(gB[h][0] + (size_t)kt * 64, lds + buf * 32768 + 16384 + h * 8192 + tid * 8);
    gl2lds16(gB[h][1] + (size_t)kt * 64, lds + buf * 32768 + 16384 + h * 8192 + 4096 + tid * 8);
  };

  const int ck0 = ((lhi) ^ (l15 & 7)) << 3;
  const int ck1 = ((4 + lhi) ^ (l15 & 7)) << 3;

  bs8 aF[4][2], bLo[2][2], bHi[2][2];

  auto RDA = [&](int buf, int mq){
#pragma unroll
    for (int m = 0; m < 4; ++m){
      const ushort_t* r = lds + buf * 32768 + wr * 8192 + ((mq + m) * 16 + l15) * 64;
      aF[m][0] = *(const bs8*)(r + ck0);
      aF[m][1] = *(const bs8*)(r + ck1);
    }
  };
  auto RDB = [&](int buf, int nq, bs8 (&br)[2][2]){
#pragma unroll
    for (int n = 0; n < 2; ++n){
      const ushort_t* r = lds + buf * 32768 + 16384 + (wc >> 1) * 8192 +
                          ((wc & 1) * 64 + (nq + n) * 16 + l15) * 64;
      br[n][0] = *(const bs8*)(r + ck0);
      br[n][1] = *(const bs8*)(r + ck1);
    }
  };
  auto MMA = [&](int mq, int nq, bs8 (&br)[2][2]){
    __builtin_amdgcn_s_setprio(1);
#pragma unroll
    for (int m = 0; m < 4; ++m)
#pragma unroll
      for (int n = 0; n < 2; ++n){
        acc[mq + m][nq + n] = __builtin_amdgcn_mfma_f32_16x16x32_bf16(aF[m][0], br[n][0], acc[mq + m][nq + n], 0, 0, 0);
        acc[mq + m][nq + n] = __builtin_amdgcn_mfma_f32_16x16x32_bf16(aF[m][1], br[n][1], acc[mq + m][nq + n], 0, 0, 0);
      }
    __builtin_amdgcn_s_setprio(0);
  };

#define BAR() __builtin_amdgcn_s_barrier()
#define LGK() asm volatile("s_waitcnt lgkmcnt(0)" ::: "memory")
#define VMC4() asm volatile("s_waitcnt vmcnt(4)" ::: "memory")

  const int nkt = K >> 6;
  const int nIter = K >> 7;

  STAGE_A(0, 0, 0); STAGE_A(0, 1, 0); STAGE_B(0, 0, 0); STAGE_B(0, 1, 0);
  STAGE_B(1, 0, 1); STAGE_B(1, 1, 1);
  VMC4();
  BAR();

  for (int it = 0; it < nIter; ++it){
    const int kt1 = 2 * it + 1;
    int kt2 = 2 * it + 2; if (kt2 > nkt - 1) kt2 = nkt - 1;
    int kt3 = 2 * it + 3; if (kt3 > nkt - 1) kt3 = nkt - 1;
    RDA(0, 0); RDB(0, 0, bLo);
    STAGE_A(1, 0, kt1);
    BAR(); LGK(); MMA(0, 0, bLo); BAR();
    RDB(0, 2, bHi);
    STAGE_A(1, 1, kt1);
    BAR(); LGK(); MMA(0, 2, bHi); BAR();
    RDA(0, 4);
    STAGE_B(0, 0, kt2);
    BAR(); LGK(); MMA(4, 0, bLo); BAR();
    STAGE_B(0, 1, kt2);
    BAR(); LGK(); MMA(4, 2, bHi);
    VMC4(); BAR();
    RDA(1, 0); RDB(1, 0, bLo);
    STAGE_A(0, 0, kt2);
    BAR(); LGK(); MMA(0, 0, bLo); BAR();
    RDB(1, 2, bHi);
    STAGE_A(0, 1, kt2);
    BAR(); LGK(); MMA(0, 2, bHi); BAR();
    RDA(1, 4);
    STAGE_B(1, 0, kt3);
    BAR(); LGK(); MMA(4, 0, bLo); BAR();
    STAGE_B(1, 1, kt3);
    BAR(); LGK(); MMA(4, 2, bHi);
    VMC4(); BAR();
  }
#undef BAR
#undef LGK
#undef VMC4
}

// EPI 1: comb1[4096][1536] + rope(kr)->Ka. EPI 2: Qa (qc+rope(qr)) pre-scaled. EPI 3: Ka(kc)+vb.
template<int EPI, typename OT>
DEV void gemm_epi(f32x4 (&acc)[8][4], OT* __restrict__ C, int N, int m0, int n0,
                  ushort_t* __restrict__ aux,
                  const float* __restrict__ fcp, const float* __restrict__ fsp){
  const int tid = threadIdx.x, lane = tid & 63, wid = tid >> 6;
  const int l15 = lane & 15, lhi = lane >> 4;
  const int wr = wid >> 2, wc = wid & 3;
  const float SC = (EPI == 2) ? (0.07216878364870323f * 1.4426950408889634f) : 1.0f;
  const int RBASE = (EPI == 1) ? 1536 : 2048;
#pragma unroll
  for (int m = 0; m < 8; ++m){
    const int r = m0 + wr * 128 + m * 16 + lhi * 4;
#pragma unroll
    for (int n = 0; n < 4; ++n){
      const int c = n0 + wc * 64 + n * 16 + l15;
      if (EPI == 0){
#pragma unroll
        for (int j = 0; j < 4; ++j)
          st_out(C, (size_t)(r + j) * N + c, acc[m][n][j]);
      } else if ((EPI == 1 && c < 1536)){
#pragma unroll
        for (int j = 0; j < 4; ++j)
          C[(size_t)(r + j) * 1536 + c] = (OT)f2bf(acc[m][n][j]);
      } else if (EPI == 2 && c < 2048){
        int hh = c >> 7, d = c & 127;
#pragma unroll
        for (int j = 0; j < 4; ++j){
          int rr = r + j, bb = rr >> 11, tt = rr & 2047;
          aux[((size_t)(bb * 16 + hh) * 2048 + tt) * 192 + d] = f2bf(acc[m][n][j] * SC);
        }
      } else if (EPI == 3 && c < 2048){
        int hh = c >> 7, d = c & 127;
#pragma unroll
        for (int j = 0; j < 4; ++j){
          int rr = r + j, bb = rr >> 11, tt = rr & 2047;
          aux[((size_t)(bb * 16 + hh) * 2048 + tt) * 192 + d] = f2bf(acc[m][n][j]);
        }
      } else if (EPI == 3){
#pragma unroll
        for (int j = 0; j < 4; ++j)
          C[(size_t)(r + j) * 2048 + (c - 2048)] = (OT)f2bf(acc[m][n][j]);
      } else {
        int cr = c - RBASE;
        int hh = cr >> 6, dr = cr & 63, ii = dr >> 1;
#pragma unroll
        for (int j = 0; j < 4; ++j){
          int rr = r + j, bb = rr >> 11, tt = rr & 2047;
          float v = acc[m][n][j] * SC;
          float pv = __shfl_xor(v, 1);
          float co = fcp[tt * 32 + ii], si = fsp[tt * 32 + ii];
          float o = (l15 & 1) ? fmaf(pv, si, v * co) : fmaf(-pv, si, v * co);
          aux[((size_t)(bb * 16 + hh) * 2048 + tt) * 192 + 128 + dr] = f2bf(o);
        }
      }
    }
  }
}

template<int EPI, typename OT>
__global__ __launch_bounds__(512, 2) void gemm256(const ushort_t* __restrict__ A, int lda,
                                                  const ushort_t* __restrict__ BT,
                                                  OT* __restrict__ C,
                                                  int M, int N, int K,
                                                  ushort_t* __restrict__ aux,
                                                  const float* __restrict__ fcp,
                                                  const float* __restrict__ fsp){
  __shared__ __align__(16) ushort_t lds[65536];
  const int nbx = M >> 8;
  const int nwg = gridDim.x;
  const int orig = blockIdx.x;
  const int wg = (orig & 7) * (nwg >> 3) + (orig >> 3);
  const int m0 = (wg % nbx) << 8;
  const int n0 = (wg / nbx) << 8;
  f32x4 acc[8][4] = {};
  gemm_core(A, lda, BT, K, m0, n0, lds, acc);
  gemm_epi<EPI, OT>(acc, C, N, m0, n0, aux, fcp, fsp);
}

// GEMM2 (192 blocks) + GEMM3 (256 blocks) fused: 448 blocks.
__global__ __launch_bounds__(512, 2) void gemm23(const ushort_t* __restrict__ A2,
                                                 const ushort_t* __restrict__ BT2,
                                                 const ushort_t* __restrict__ A3,
                                                 const ushort_t* __restrict__ BT3,
                                                 ushort_t* __restrict__ vb,
                                                 ushort_t* __restrict__ Qa,
                                                 ushort_t* __restrict__ Ka,
                                                 const float* __restrict__ fcp,
                                                 const float* __restrict__ fsp){
  __shared__ __align__(16) ushort_t lds[65536];
  const int nwg = gridDim.x;   // 448
  const int orig = blockIdx.x;
  const int wg = (orig & 7) * (nwg >> 3) + (orig >> 3);
  f32x4 acc[8][4] = {};
  if (wg < 192){
    const int m0 = (wg % 16) << 8, n0 = (wg / 16) << 8;
    gemm_core(A2, 1536, BT2, 1024, m0, n0, lds, acc);
    gemm_epi<2, ushort_t>(acc, nullptr, 3072, m0, n0, Qa, fcp, fsp);
  } else {
    const int g = wg - 192;
    const int m0 = (g % 16) << 8, n0 = (g / 16) << 8;
    gemm_core(A3, 1536, BT3, 512, m0, n0, lds, acc);
    gemm_epi<3, ushort_t>(acc, vb, 4096, m0, n0, Ka, fcp, fsp);
  }
}

// ============ GEMM4: 256x128-tile 8-phase core, fp32 out (exact 256-block fill) ============
__global__ __launch_bounds__(512, 1) void gemm4_128(const ushort_t* __restrict__ A, int lda,
                                                    const ushort_t* __restrict__ BT,
                                                    float* __restrict__ C,
                                                    int M, int N, int K){
  __shared__ __align__(16) ushort_t lds[49152];   // 96 KiB: per buf A 256x64 | B 128x64
  const int tid = threadIdx.x, lane = tid & 63, wid = tid >> 6;
  const int l15 = lane & 15, lhi = lane >> 4;
  const int wr = wid >> 1, wc = wid & 1;

  const int nbx = M >> 8;
  const int nwg = gridDim.x;
  const int orig = blockIdx.x;
  const int wg = (orig & 7) * (nwg >> 3) + (orig >> 3);
  const int m0 = (wg % nbx) << 8;
  const int n0 = (wg / nbx) << 7;

  const int trow = tid >> 3;
  const int tcsrc = (tid & 7) ^ (trow & 7);
  const ushort_t* gA[2][2];
  const ushort_t* gB[2];
#pragma unroll
  for (int h = 0; h < 2; ++h)
#pragma unroll
    for (int i = 0; i < 2; ++i)
      gA[h][i] = A + (size_t)(m0 + h * 128 + i * 64 + trow) * lda + tcsrc * 8;
#pragma unroll
  for (int i = 0; i < 2; ++i)
    gB[i] = BT + (size_t)(n0 + i * 64 + trow) * K + tcsrc * 8;

  auto STAGE_A = [&](int buf, int h, int kt){
    gl2lds16(gA[h][0] + (size_t)kt * 64, lds + buf * 24576 + h * 8192 + tid * 8);
    gl2lds16(gA[h][1] + (size_t)kt * 64, lds + buf * 24576 + h * 8192 + 4096 + tid * 8);
  };
  auto STAGE_B = [&](int buf, int kt){
    gl2lds16(gB[0] + (size_t)kt * 64, lds + buf * 24576 + 16384 + tid * 8);
    gl2lds16(gB[1] + (size_t)kt * 64, lds + buf * 24576 + 16384 + 4096 + tid * 8);
  };

  const int ck0 = ((lhi) ^ (l15 & 7)) << 3;
  const int ck1 = ((4 + lhi) ^ (l15 & 7)) << 3;

  f32x4 acc[4][4] = {};
  bs8 aF[2][2], bLo[2][2], bHi[2][2];

  auto RDA = [&](int buf, int mq){
#pragma unroll
    for (int m = 0; m < 2; ++m){
      const int rowin = (wr & 1) * 64 + (mq + m) * 16 + l15;
      const ushort_t* r = lds + buf * 24576 + (wr >> 1) * 8192 + rowin * 64;
      aF[m][0] = *(const bs8*)(r + ck0);
      aF[m][1] = *(const bs8*)(r + ck1);
    }
  };
  auto RDB = [&](int buf, int nq, bs8 (&br)[2][2]){
#pragma unroll
    for (int n = 0; n < 2; ++n){
      const int row = wc * 64 + (nq + n) * 16 + l15;
      const ushort_t* r = lds + buf * 24576 + 16384 + row * 64;
      br[n][0] = *(const bs8*)(r + ck0);
      br[n][1] = *(const bs8*)(r + ck1);
    }
  };
  auto MMA = [&](int mq, int nq, bs8 (&br)[2][2]){
    __builtin_amdgcn_s_setprio(1);
#pragma unroll
    for (int m = 0; m < 2; ++m)
#pragma unroll
      for (int n = 0; n < 2; ++n){
        acc[mq + m][nq + n] = __builtin_amdgcn_mfma_f32_16x16x32_bf16(aF[m][0], br[n][0], acc[mq + m][nq + n], 0, 0, 0);
        acc[mq + m][nq + n] = __builtin_amdgcn_mfma_f32_16x16x32_bf16(aF[m][1], br[n][1], acc[mq + m][nq + n], 0, 0, 0);
      }
    __builtin_amdgcn_s_setprio(0);
  };

#define BAR() __builtin_amdgcn_s_barrier()
#define LGK() asm volatile("s_waitcnt lgkmcnt(0)" ::: "memory")
#define VMC2() asm volatile("s_waitcnt vmcnt(2)" ::: "memory")

  const int nkt = K >> 6;
  const int nIter = K >> 7;

  // prologue: kt0 A+B (6 loads) then kt1 B (2) -> wait oldest 6 => VMC(2)
  STAGE_A(0, 0, 0); STAGE_A(0, 1, 0); STAGE_B(0, 0);
  STAGE_B(1, 1);
  VMC2();
  BAR();

  for (int it = 0; it < nIter; ++it){
    const int kt1 = 2 * it + 1;
    int kt2 = 2 * it + 2; if (kt2 > nkt - 1) kt2 = nkt - 1;
    int kt3 = 2 * it + 3; if (kt3 > nkt - 1) kt3 = nkt - 1;
    // ph1
    RDA(0, 0); RDB(0, 0, bLo);
    STAGE_A(1, 0, kt1);
    BAR(); LGK(); MMA(0, 0, bLo); BAR();
    // ph2
    RDB(0, 2, bHi);
    STAGE_A(1, 1, kt1);
    BAR(); LGK(); MMA(0, 2, bHi); BAR();
    // ph3
    RDA(0, 2);
    STAGE_B(0, kt2);
    BAR(); LGK(); MMA(2, 0, bLo); BAR();
    // ph4  (outstanding: A(kt1)=4 + B(kt2)=2 -> wait A(kt1) => VMC(2))
    BAR(); LGK(); MMA(2, 2, bHi);
    VMC2(); BAR();
    // ph5
    RDA(1, 0); RDB(1, 0, bLo);
    STAGE_A(0, 0, kt2);
    BAR(); LGK(); MMA(0, 0, bLo); BAR();
    // ph6
    RDB(1, 2, bHi);
    STAGE_A(0, 1, kt2);
    BAR(); LGK(); MMA(0, 2, bHi); BAR();
    // ph7
    RDA(1, 2);
    STAGE_B(1, kt3);
    BAR(); LGK(); MMA(2, 0, bLo); BAR();
    // ph8
    BAR(); LGK(); MMA(2, 2, bHi);
    VMC2(); BAR();
  }
#undef BAR
#undef LGK
#undef VMC2

#pragma unroll
  for (int m = 0; m < 4; ++m){
    const int r = m0 + wr * 64 + m * 16 + lhi * 4;
#pragma unroll
    for (int n = 0; n < 4; ++n){
      const int c = n0 + wc * 64 + n * 16 + l15;
#pragma unroll
      for (int j = 0; j < 4; ++j)
        C[(size_t)(r + j) * N + c] = acc[m][n][j];
    }
  }
}

// ====== flash attention v5 (reverted from failed v6): 8 waves x 16q, two uniform q-tiles ======
__global__ __launch_bounds__(512, 1) void attn_kernel(const ushort_t* __restrict__ Qa,
                                                      const ushort_t* __restrict__ Ka,
                                                      const ushort_t* __restrict__ VT,
                                                      ushort_t* __restrict__ O){
  // [K0 12288 | K1 12288 | V0 8192 | V1 8192] elems = 80 KB
  __shared__ __align__(16) ushort_t lds[40960];
  const int tid = threadIdx.x, lane = tid & 63, wid = tid >> 6;
  const int bh = blockIdx.x, p = blockIdx.y;
  const int b = bh >> 4, h = bh & 15;
  const int qb0 = 15 - p, qb1 = p;
  const int nkt0 = 2 * qb0 + 2;
  const int NT = 34;
  const int l15 = lane & 15, lhi = lane >> 4;

  const ushort_t* Kbh = Ka + (size_t)bh * 2048 * 192;
  const ushort_t* Vbh = VT + (size_t)bh * 128 * 2048;

  const ushort_t* ksrc[3];
#pragma unroll
  for (int i = 0; i < 3; ++i){
    int c = i * 512 + tid;
    int row = c / 24, col = c % 24;
    int hk = (row & 3) | (((row >> 3) & 1) << 2);
    ksrc[i] = Kbh + (size_t)row * 192 + (col ^ hk) * 8;
  }
  const ushort_t* vsrc[2];
#pragma unroll
  for (int i = 0; i < 2; ++i){
    int c = i * 512 + tid;
    int d = c >> 3, col = c & 7;
    vsrc[i] = Vbh + (size_t)d * 2048 + (col ^ (d & 7)) * 8;
  }

  auto STAGE = [&](int ft, int buf){
    int kt = (ft < nkt0) ? ft : ft - nkt0;
#pragma unroll
    for (int i = 0; i < 3; ++i)
      gl2lds16(ksrc[i] + (size_t)kt * 12288, lds + buf * 12288 + (i * 512 + tid) * 8);
#pragma unroll
    for (int i = 0; i < 2; ++i)
      gl2lds16(vsrc[i] + kt * 64, lds + 24576 + buf * 8192 + (i * 512 + tid) * 8);
  };

  bs8 qf[6];
  auto LOADQ = [&](int qb){
    const size_t qrow = ((size_t)bh * 2048 + qb * 128 + wid * 16 + l15) * 192;
#pragma unroll
    for (int kc = 0; kc < 6; ++kc)
      qf[kc] = *(const bs8*)(Qa + qrow + kc * 32 + lhi * 8);
  };

  f32x4 acc[8] = {};
  float mrow = -1e30f, lrow = 0.f;

  auto EPI = [&](int qb){
    float rl = 1.0f / lrow;
    int t = qb * 128 + wid * 16 + l15;
#pragma unroll
    for (int f = 0; f < 8; ++f){
      u16x4 o;
#pragma unroll
      for (int j = 0; j < 4; ++j) o[j] = f2bf(acc[f][j] * rl);
      *(u16x4*)(O + ((size_t)b * 2048 + t) * 2048 + h * 128 + f * 16 + lhi * 4) = o;
    }
  };

  const int hkr = (l15 & 3) | (((l15 >> 2) & 1) << 2);

#define BARR() __builtin_amdgcn_s_barrier()
#define LGK0() asm volatile("s_waitcnt lgkmcnt(0)" ::: "memory")
#define VMC(n) asm volatile("s_waitcnt vmcnt(" #n ")" ::: "memory")

  LOADQ(qb0);
  STAGE(0, 0);
  STAGE(1, 1);
  VMC(5);
  BARR();

  for (int ft = 0; ft < NT; ++ft){
    if (ft == nkt0){
      EPI(qb0);
#pragma unroll
      for (int f = 0; f < 8; ++f) acc[f] = (f32x4){0.f, 0.f, 0.f, 0.f};
      mrow = -1e30f; lrow = 0.f;
      LOADQ(qb1);
    }
    const int seg = (ft >= nkt0) ? 1 : 0;
    const int kt = seg ? ft - nkt0 : ft;
    const int qb = seg ? qb1 : qb0;
    const int qm0 = qb << 7;
    const int mylast = 2 * qb + (wid >> 2);
    const int cur = ft & 1;
    const ushort_t* Kb = lds + cur * 12288;
    const ushort_t* Vb = lds + 24576 + cur * 8192;

    if (kt <= mylast){
      f32x4 s[4] = {};
      __builtin_amdgcn_s_setprio(1);
#pragma unroll
      for (int kc = 0; kc < 6; ++kc){
        bs8 kf4[4];
#pragma unroll
        for (int m = 0; m < 4; ++m){
          int row = ((m >> 1) << 5) + ((l15 >> 2) << 3) + ((m & 1) << 2) + (l15 & 3);
          kf4[m] = *(const bs8*)(Kb + row * 192 + (((kc * 4 + lhi) ^ hkr) << 3));
        }
#pragma unroll
        for (int m = 0; m < 4; ++m)
          s[m] = __builtin_amdgcn_mfma_f32_16x16x32_bf16(kf4[m], qf[kc], s[m], 0, 0, 0);
      }
      __builtin_amdgcn_s_setprio(0);

      const bool noMask = (kt * 64 + 63) <= (qm0 + wid * 16);
      const int qi = qm0 + wid * 16 + l15;
      float rmax = -3e38f;
#pragma unroll
      for (int m = 0; m < 4; ++m)
#pragma unroll
        for (int j = 0; j < 4; ++j){
          float sv = s[m][j];
          if (!noMask){
            int ki = kt * 64 + ((m >> 1) << 5) + (lhi << 3) + ((m & 1) << 2) + j;
            if (ki > qi) sv = -3e38f;
          }
          s[m][j] = sv;
          rmax = fmaxf(rmax, sv);
        }
      rmax = fmaxf(rmax, __shfl_xor(rmax, 16));
      rmax = fmaxf(rmax, __shfl_xor(rmax, 32));
      if (!__all(rmax <= mrow + 8.f)){
        float mnew = fmaxf(mrow, rmax);
        float osc = exp2f(mrow - mnew);
        lrow *= osc;
#pragma unroll
        for (int f = 0; f < 8; ++f) acc[f] *= osc;
        mrow = mnew;
      }
      float rsum = 0.f;
#pragma unroll
      for (int m = 0; m < 4; ++m)
#pragma unroll
        for (int j = 0; j < 4; ++j){
          float pv = exp2f(s[m][j] - mrow);
          s[m][j] = pv;
          rsum += pv;
        }
      rsum += __shfl_xor(rsum, 16);
      rsum += __shfl_xor(rsum, 32);
      lrow += rsum;

      bs8 pb[2];
#pragma unroll
      for (int kc2 = 0; kc2 < 2; ++kc2){
        union { bs8 v; unsigned u[4]; } pu;
#pragma unroll
        for (int half = 0; half < 2; ++half){
          const f32x4& sv = s[2 * kc2 + half];
          pu.u[2 * half]     = cvt_pk_bf16(sv[0], sv[1]);
          pu.u[2 * half + 1] = cvt_pk_bf16(sv[2], sv[3]);
        }
        pb[kc2] = pu.v;
      }

      __builtin_amdgcn_s_setprio(1);
#pragma unroll
      for (int kc2 = 0; kc2 < 2; ++kc2)
#pragma unroll
        for (int f = 0; f < 8; ++f){
          bs8 vf = *(const bs8*)(Vb + (f * 16 + l15) * 64 + (((kc2 * 4 + lhi) ^ (l15 & 7)) << 3));
          acc[f] = __builtin_amdgcn_mfma_f32_16x16x32_bf16(vf, pb[kc2], acc[f], 0, 0, 0);
        }
      __builtin_amdgcn_s_setprio(0);
    }

    LGK0();
    BARR();
    if (ft + 2 < NT){
      STAGE(ft + 2, cur);
      VMC(5);
    } else {
      VMC(0);
    }
    BARR();
  }
#undef BARR
#undef LGK0
#undef VMC

  EPI(qb1);
}

extern "C" void kernel_launch(void* const* d_in, const int* in_sizes, int n_in,
                              void* d_out, int out_size, void* d_ws, size_t ws_size,
                              hipStream_t stream){
  constexpr int Bc = 2, Tc = 2048, Cc = 2048, Hc = 16, HDc = 128, RDc = 64, KVRc = 512, QRc = 1024;
  constexpr int Mx = Bc * Tc; // 4096
  const float* x     = (const float*)d_in[0];
  const float* w_dq  = (const float*)d_in[1];
  const float* w_uq  = (const float*)d_in[2];
  const float* w_dkv = (const float*)d_in[3];
  const float* w_uk  = (const float*)d_in[4];
  const float* w_uv  = (const float*)d_in[5];
  const float* w_qr  = (const float*)d_in[6];
  const float* w_kr  = (const float*)d_in[7];
  const float* w_o   = (const float*)d_in[8];
  const float* fc    = (const float*)d_in[9];
  const float* fs    = (const float*)d_in[10];
  float* out = (float*)d_out;

  char* ws = (char*)d_ws;
  size_t off = 0;
  auto alloc = [&](size_t elems) -> ushort_t* {
    ushort_t* p = (ushort_t*)(ws + off);
    off += ((elems * 2) + 255) & ~(size_t)255;
    return p;
  };
  ushort_t* xb    = alloc((size_t)Mx * Cc);
  ushort_t* wdqT  = alloc((size_t)QRc * Cc);
  ushort_t* wdkvT = alloc((size_t)KVRc * Cc);
  ushort_t* wkrT  = alloc((size_t)(Hc * RDc) * Cc);
  ushort_t* wuqT  = alloc((size_t)(Hc * HDc) * QRc);
  ushort_t* wqrT  = alloc((size_t)(Hc * RDc) * QRc);
  ushort_t* wukT  = alloc((size_t)(Hc * HDc) * KVRc);
  ushort_t* wuvT  = alloc((size_t)(Hc * HDc) * KVRc);
  ushort_t* woT   = alloc((size_t)Cc * (Hc * HDc));
  ushort_t* comb1 = alloc((size_t)Mx * 1536);   // [cq 1024 | ckv 512]
  ushort_t* vb    = alloc((size_t)Mx * 2048);   // v (pre-transpose)
  ushort_t* Qa    = alloc((size_t)Bc * Hc * Tc * 192);
  ushort_t* Ka    = alloc((size_t)Bc * Hc * Tc * 192);
  ushort_t* vT    = alloc((size_t)Bc * Hc * HDc * Tc);
  ushort_t* O     = xb;  // alias: xb dead after GEMM1

  cast_x<<<dim3(((size_t)Mx * Cc) / 1024), 256, 0, stream>>>(x, xb);

  tcast_all<<<dim3(14336), 256, 0, stream>>>(w_dq, w_dkv, w_kr, w_uq, w_qr, w_uk, w_uv, w_o,
                                             wdqT, wdkvT, wkrT, wuqT, wqrT, wukT, wuvT, woT);

  // GEMM1: x @ [w_dq|w_dkv|w_kr] -> comb1[.][1536] + rope(kr)->Ka[..][128..192)
  gemm256<1, ushort_t><<<dim3((Mx / 256) * (2560 / 256)), 512, 0, stream>>>(
      xb, Cc, wdqT, comb1, Mx, 2560, Cc, Ka, fc, fs);
  // GEMM2+3 fused: cq @ [w_uq|w_qr] -> Qa ; ckv @ [w_uk|w_uv] -> Ka(kc) + vb
  gemm23<<<dim3(448), 512, 0, stream>>>(comb1, wuqT, comb1 + QRc, wukT, vb, Qa, Ka, fc, fs);

  transpose_v<<<dim3(Tc / 32, HDc / 32, Bc * Hc), dim3(32, 8), 0, stream>>>(vb, 2048, vT);

  attn_kernel<<<dim3(Bc * Hc, 8), 512, 0, stream>>>(Qa, Ka, vT, O);

  // GEMM4: O @ w_o -> out [4096][2048] fp32, 256x128 tiles = 256 blocks (full fill)
  gemm4_128<<<dim3(256), 512, 0, stream>>>(O, Hc * HDc, woT, out, Mx, Cc, Hc * HDc);
}

// Round 9
// 285.403 us; speedup vs baseline: 1.1698x; 1.0740x over previous
//
#include <hip/hip_runtime.h>

typedef unsigned short ushort_t;
typedef __attribute__((ext_vector_type(8))) short bs8;       // 8 x bf16 (4 VGPR)
typedef __attribute__((ext_vector_type(4))) float f32x4;
typedef __attribute__((ext_vector_type(4))) unsigned short u16x4;

#define DEV __device__ __forceinline__

DEV unsigned short f2bf(float f){
  unsigned u = __float_as_uint(f);
  u += 0x7fffu + ((u >> 16) & 1u);           // round-to-nearest-even
  return (unsigned short)(u >> 16);
}
DEV float bf2f(unsigned short h){ return __uint_as_float(((unsigned)h) << 16); }

DEV unsigned cvt_pk_bf16(float lo, float hi){
  unsigned r;
  asm volatile("v_cvt_pk_bf16_f32 %0, %1, %2" : "=v"(r) : "v"(lo), "v"(hi));
  return r;
}

DEV void gl2lds16(const void* g, void* l){
  __builtin_amdgcn_global_load_lds((const __attribute__((address_space(1))) void*)g,
                                   (__attribute__((address_space(3))) void*)l, 16, 0, 0);
}

DEV void st_out(ushort_t* C, size_t i, float v){ C[i] = f2bf(v); }
DEV void st_out(float*    C, size_t i, float v){ C[i] = v; }

// ---------------- cast x (fp32 -> bf16), 4 elems/thread ----------------
__global__ __launch_bounds__(256) void cast_x(const float* __restrict__ in,
                                              ushort_t* __restrict__ outb){
  size_t i = ((size_t)blockIdx.x * 256 + threadIdx.x) * 4;
  float4 v = *(const float4*)(in + i);
  u16x4 o;
  o[0] = f2bf(v.x); o[1] = f2bf(v.y); o[2] = f2bf(v.z); o[3] = f2bf(v.w);
  *(u16x4*)(outb + i) = o;
}

// ---------------- ALL weight transpose-casts in one dispatch ----------------
__global__ __launch_bounds__(256) void tcast_all(
    const float* __restrict__ s0, const float* __restrict__ s1,
    const float* __restrict__ s2, const float* __restrict__ s3,
    const float* __restrict__ s4, const float* __restrict__ s5,
    const float* __restrict__ s6, const float* __restrict__ s7,
    ushort_t* __restrict__ d0, ushort_t* __restrict__ d1,
    ushort_t* __restrict__ d2, ushort_t* __restrict__ d3,
    ushort_t* __restrict__ d4, ushort_t* __restrict__ d5,
    ushort_t* __restrict__ d6, ushort_t* __restrict__ d7){
  __shared__ float tile[32][33];
  const int bid = blockIdx.x;
  const float* src; ushort_t* dst; int K, N, loc;
  if      (bid <  2048){ src=s0; dst=d0; K=2048; N=1024; loc=bid; }
  else if (bid <  3072){ src=s1; dst=d1; K=2048; N=512;  loc=bid-2048; }
  else if (bid <  5120){ src=s2; dst=d2; K=2048; N=1024; loc=bid-3072; }
  else if (bid <  7168){ src=s3; dst=d3; K=1024; N=2048; loc=bid-5120; }
  else if (bid <  8192){ src=s4; dst=d4; K=1024; N=1024; loc=bid-7168; }
  else if (bid <  9216){ src=s5; dst=d5; K=512;  N=2048; loc=bid-8192; }
  else if (bid < 10240){ src=s6; dst=d6; K=512;  N=2048; loc=bid-9216; }
  else                 { src=s7; dst=d7; K=2048; N=2048; loc=bid-10240; }
  const int nx = N >> 5;
  const int n0 = (loc % nx) << 5, k0 = (loc / nx) << 5;
  const int tx = threadIdx.x & 31, ty = threadIdx.x >> 5;
  for (int r = ty; r < 32; r += 8)
    tile[r][tx] = src[(size_t)(k0 + r) * N + n0 + tx];
  __syncthreads();
  for (int r = ty; r < 32; r += 8)
    dst[(size_t)(n0 + r) * K + k0 + tx] = f2bf(tile[tx][r]);
}

// ================= 256x256 8-phase GEMM core (T2+T3+T4+T5), BK=64 =================
DEV void gemm_core(const ushort_t* __restrict__ A, int lda,
                   const ushort_t* __restrict__ BT, int K,
                   int m0, int n0, ushort_t* lds, f32x4 (&acc)[8][4]){
  const int tid = threadIdx.x, lane = tid & 63, wid = tid >> 6;
  const int l15 = lane & 15, lhi = lane >> 4;
  const int wr = wid >> 2, wc = wid & 3;

  const int trow = tid >> 3;
  const int tcsrc = (tid & 7) ^ (trow & 7);
  const ushort_t* gA[2][2];
  const ushort_t* gB[2][2];
#pragma unroll
  for (int h = 0; h < 2; ++h)
#pragma unroll
    for (int i = 0; i < 2; ++i){
      gA[h][i] = A  + (size_t)(m0 + h * 128 + i * 64 + trow) * lda + tcsrc * 8;
      gB[h][i] = BT + (size_t)(n0 + h * 128 + i * 64 + trow) * K   + tcsrc * 8;
    }

  auto STAGE_A = [&](int buf, int h, int kt){
    gl2lds16(gA[h][0] + (size_t)kt * 64, lds + buf * 32768 + h * 8192 + tid * 8);
    gl2lds16(gA[h][1] + (size_t)kt * 64, lds + buf * 32768 + h * 8192 + 4096 + tid * 8);
  };
  auto STAGE_B = [&](int buf, int h, int kt){
    gl2lds16(gB[h][0] + (size_t)kt * 64, lds + buf * 32768 + 16384 + h * 8192 + tid * 8);
    gl2lds16(gB[h][1] + (size_t)kt * 64, lds + buf * 32768 + 16384 + h * 8192 + 4096 + tid * 8);
  };

  const int ck0 = ((lhi) ^ (l15 & 7)) << 3;
  const int ck1 = ((4 + lhi) ^ (l15 & 7)) << 3;

  bs8 aF[4][2], bLo[2][2], bHi[2][2];

  auto RDA = [&](int buf, int mq){
#pragma unroll
    for (int m = 0; m < 4; ++m){
      const ushort_t* r = lds + buf * 32768 + wr * 8192 + ((mq + m) * 16 + l15) * 64;
      aF[m][0] = *(const bs8*)(r + ck0);
      aF[m][1] = *(const bs8*)(r + ck1);
    }
  };
  auto RDB = [&](int buf, int nq, bs8 (&br)[2][2]){
#pragma unroll
    for (int n = 0; n < 2; ++n){
      const ushort_t* r = lds + buf * 32768 + 16384 + (wc >> 1) * 8192 +
                          ((wc & 1) * 64 + (nq + n) * 16 + l15) * 64;
      br[n][0] = *(const bs8*)(r + ck0);
      br[n][1] = *(const bs8*)(r + ck1);
    }
  };
  auto MMA = [&](int mq, int nq, bs8 (&br)[2][2]){
    __builtin_amdgcn_s_setprio(1);
#pragma unroll
    for (int m = 0; m < 4; ++m)
#pragma unroll
      for (int n = 0; n < 2; ++n){
        acc[mq + m][nq + n] = __builtin_amdgcn_mfma_f32_16x16x32_bf16(aF[m][0], br[n][0], acc[mq + m][nq + n], 0, 0, 0);
        acc[mq + m][nq + n] = __builtin_amdgcn_mfma_f32_16x16x32_bf16(aF[m][1], br[n][1], acc[mq + m][nq + n], 0, 0, 0);
      }
    __builtin_amdgcn_s_setprio(0);
  };

#define BAR() __builtin_amdgcn_s_barrier()
#define LGK() asm volatile("s_waitcnt lgkmcnt(0)" ::: "memory")
#define VMC4() asm volatile("s_waitcnt vmcnt(4)" ::: "memory")

  const int nkt = K >> 6;
  const int nIter = K >> 7;

  STAGE_A(0, 0, 0); STAGE_A(0, 1, 0); STAGE_B(0, 0, 0); STAGE_B(0, 1, 0);
  STAGE_B(1, 0, 1); STAGE_B(1, 1, 1);
  VMC4();
  BAR();

  for (int it = 0; it < nIter; ++it){
    const int kt1 = 2 * it + 1;
    int kt2 = 2 * it + 2; if (kt2 > nkt - 1) kt2 = nkt - 1;
    int kt3 = 2 * it + 3; if (kt3 > nkt - 1) kt3 = nkt - 1;
    RDA(0, 0); RDB(0, 0, bLo);
    STAGE_A(1, 0, kt1);
    BAR(); LGK(); MMA(0, 0, bLo); BAR();
    RDB(0, 2, bHi);
    STAGE_A(1, 1, kt1);
    BAR(); LGK(); MMA(0, 2, bHi); BAR();
    RDA(0, 4);
    STAGE_B(0, 0, kt2);
    BAR(); LGK(); MMA(4, 0, bLo); BAR();
    STAGE_B(0, 1, kt2);
    BAR(); LGK(); MMA(4, 2, bHi);
    VMC4(); BAR();
    RDA(1, 0); RDB(1, 0, bLo);
    STAGE_A(0, 0, kt2);
    BAR(); LGK(); MMA(0, 0, bLo); BAR();
    RDB(1, 2, bHi);
    STAGE_A(0, 1, kt2);
    BAR(); LGK(); MMA(0, 2, bHi); BAR();
    RDA(1, 4);
    STAGE_B(1, 0, kt3);
    BAR(); LGK(); MMA(4, 0, bLo); BAR();
    STAGE_B(1, 1, kt3);
    BAR(); LGK(); MMA(4, 2, bHi);
    VMC4(); BAR();
  }
#undef BAR
#undef LGK
#undef VMC4
}

// EPI 1: comb1[4096][1536] + rope(kr)->Ka. EPI 2: Qa (qc+rope(qr)) pre-scaled.
// EPI 3: Ka(kc) + v directly transposed -> vT[bh][d][t] (C = vT).
template<int EPI, typename OT>
DEV void gemm_epi(f32x4 (&acc)[8][4], OT* __restrict__ C, int N, int m0, int n0,
                  ushort_t* __restrict__ aux,
                  const float* __restrict__ fcp, const float* __restrict__ fsp){
  const int tid = threadIdx.x, lane = tid & 63, wid = tid >> 6;
  const int l15 = lane & 15, lhi = lane >> 4;
  const int wr = wid >> 2, wc = wid & 3;
  const float SC = (EPI == 2) ? (0.07216878364870323f * 1.4426950408889634f) : 1.0f;
  const int RBASE = (EPI == 1) ? 1536 : 2048;
#pragma unroll
  for (int m = 0; m < 8; ++m){
    const int r = m0 + wr * 128 + m * 16 + lhi * 4;
#pragma unroll
    for (int n = 0; n < 4; ++n){
      const int c = n0 + wc * 64 + n * 16 + l15;
      if (EPI == 0){
#pragma unroll
        for (int j = 0; j < 4; ++j)
          st_out(C, (size_t)(r + j) * N + c, acc[m][n][j]);
      } else if ((EPI == 1 && c < 1536)){
#pragma unroll
        for (int j = 0; j < 4; ++j)
          C[(size_t)(r + j) * 1536 + c] = (OT)f2bf(acc[m][n][j]);
      } else if (EPI == 2 && c < 2048){
        int hh = c >> 7, d = c & 127;
#pragma unroll
        for (int j = 0; j < 4; ++j){
          int rr = r + j, bb = rr >> 11, tt = rr & 2047;
          aux[((size_t)(bb * 16 + hh) * 2048 + tt) * 192 + d] = f2bf(acc[m][n][j] * SC);
        }
      } else if (EPI == 3 && c < 2048){
        int hh = c >> 7, d = c & 127;
#pragma unroll
        for (int j = 0; j < 4; ++j){
          int rr = r + j, bb = rr >> 11, tt = rr & 2047;
          aux[((size_t)(bb * 16 + hh) * 2048 + tt) * 192 + d] = f2bf(acc[m][n][j]);
        }
      } else if (EPI == 3){
        // v region -> vT[bh][d][t]: j-quad = 4 contiguous t (aligned 8B store)
        int cv = c - 2048;
        int hh = cv >> 7, d = cv & 127;
        int bb = r >> 11, tt = r & 2047;
        u16x4 o;
#pragma unroll
        for (int j = 0; j < 4; ++j) o[j] = f2bf(acc[m][n][j]);
        *(u16x4*)((ushort_t*)C + ((size_t)(bb * 16 + hh) * 128 + d) * 2048 + tt) = o;
      } else {
        int cr = c - RBASE;
        int hh = cr >> 6, dr = cr & 63, ii = dr >> 1;
#pragma unroll
        for (int j = 0; j < 4; ++j){
          int rr = r + j, bb = rr >> 11, tt = rr & 2047;
          float v = acc[m][n][j] * SC;
          float pv = __shfl_xor(v, 1);
          float co = fcp[tt * 32 + ii], si = fsp[tt * 32 + ii];
          float o = (l15 & 1) ? fmaf(pv, si, v * co) : fmaf(-pv, si, v * co);
          aux[((size_t)(bb * 16 + hh) * 2048 + tt) * 192 + 128 + dr] = f2bf(o);
        }
      }
    }
  }
}

template<int EPI, typename OT>
__global__ __launch_bounds__(512, 2) void gemm256(const ushort_t* __restrict__ A, int lda,
                                                  const ushort_t* __restrict__ BT,
                                                  OT* __restrict__ C,
                                                  int M, int N, int K,
                                                  ushort_t* __restrict__ aux,
                                                  const float* __restrict__ fcp,
                                                  const float* __restrict__ fsp){
  __shared__ __align__(16) ushort_t lds[65536];
  const int nbx = M >> 8;
  const int nwg = gridDim.x;
  const int orig = blockIdx.x;
  const int wg = (orig & 7) * (nwg >> 3) + (orig >> 3);
  const int m0 = (wg % nbx) << 8;
  const int n0 = (wg / nbx) << 8;
  f32x4 acc[8][4] = {};
  gemm_core(A, lda, BT, K, m0, n0, lds, acc);
  gemm_epi<EPI, OT>(acc, C, N, m0, n0, aux, fcp, fsp);
}

// GEMM2 (192 blocks) + GEMM3 (256 blocks) fused: 448 blocks.
__global__ __launch_bounds__(512, 2) void gemm23(const ushort_t* __restrict__ A2,
                                                 const ushort_t* __restrict__ BT2,
                                                 const ushort_t* __restrict__ A3,
                                                 const ushort_t* __restrict__ BT3,
                                                 ushort_t* __restrict__ vT,
                                                 ushort_t* __restrict__ Qa,
                                                 ushort_t* __restrict__ Ka,
                                                 const float* __restrict__ fcp,
                                                 const float* __restrict__ fsp){
  __shared__ __align__(16) ushort_t lds[65536];
  const int nwg = gridDim.x;   // 448
  const int orig = blockIdx.x;
  const int wg = (orig & 7) * (nwg >> 3) + (orig >> 3);
  f32x4 acc[8][4] = {};
  if (wg < 192){
    const int m0 = (wg % 16) << 8, n0 = (wg / 16) << 8;
    gemm_core(A2, 1536, BT2, 1024, m0, n0, lds, acc);
    gemm_epi<2, ushort_t>(acc, nullptr, 3072, m0, n0, Qa, fcp, fsp);
  } else {
    const int g = wg - 192;
    const int m0 = (g % 16) << 8, n0 = (g / 16) << 8;
    gemm_core(A3, 1536, BT3, 512, m0, n0, lds, acc);
    gemm_epi<3, ushort_t>(acc, vT, 4096, m0, n0, Ka, fcp, fsp);
  }
}

// ============ GEMM4: 256x128-tile 8-phase core, fp32 out (exact 256-block fill) ============
__global__ __launch_bounds__(512, 1) void gemm4_128(const ushort_t* __restrict__ A, int lda,
                                                    const ushort_t* __restrict__ BT,
                                                    float* __restrict__ C,
                                                    int M, int N, int K){
  __shared__ __align__(16) ushort_t lds[49152];   // 96 KiB: per buf A 256x64 | B 128x64
  const int tid = threadIdx.x, lane = tid & 63, wid = tid >> 6;
  const int l15 = lane & 15, lhi = lane >> 4;
  const int wr = wid >> 1, wc = wid & 1;

  const int nbx = M >> 8;
  const int nwg = gridDim.x;
  const int orig = blockIdx.x;
  const int wg = (orig & 7) * (nwg >> 3) + (orig >> 3);
  const int m0 = (wg % nbx) << 8;
  const int n0 = (wg / nbx) << 7;

  const int trow = tid >> 3;
  const int tcsrc = (tid & 7) ^ (trow & 7);
  const ushort_t* gA[2][2];
  const ushort_t* gB[2];
#pragma unroll
  for (int h = 0; h < 2; ++h)
#pragma unroll
    for (int i = 0; i < 2; ++i)
      gA[h][i] = A + (size_t)(m0 + h * 128 + i * 64 + trow) * lda + tcsrc * 8;
#pragma unroll
  for (int i = 0; i < 2; ++i)
    gB[i] = BT + (size_t)(n0 + i * 64 + trow) * K + tcsrc * 8;

  auto STAGE_A = [&](int buf, int h, int kt){
    gl2lds16(gA[h][0] + (size_t)kt * 64, lds + buf * 24576 + h * 8192 + tid * 8);
    gl2lds16(gA[h][1] + (size_t)kt * 64, lds + buf * 24576 + h * 8192 + 4096 + tid * 8);
  };
  auto STAGE_B = [&](int buf, int kt){
    gl2lds16(gB[0] + (size_t)kt * 64, lds + buf * 24576 + 16384 + tid * 8);
    gl2lds16(gB[1] + (size_t)kt * 64, lds + buf * 24576 + 16384 + 4096 + tid * 8);
  };

  const int ck0 = ((lhi) ^ (l15 & 7)) << 3;
  const int ck1 = ((4 + lhi) ^ (l15 & 7)) << 3;

  f32x4 acc[4][4] = {};
  bs8 aF[2][2], bLo[2][2], bHi[2][2];

  auto RDA = [&](int buf, int mq){
#pragma unroll
    for (int m = 0; m < 2; ++m){
      const int rowin = (wr & 1) * 64 + (mq + m) * 16 + l15;
      const ushort_t* r = lds + buf * 24576 + (wr >> 1) * 8192 + rowin * 64;
      aF[m][0] = *(const bs8*)(r + ck0);
      aF[m][1] = *(const bs8*)(r + ck1);
    }
  };
  auto RDB = [&](int buf, int nq, bs8 (&br)[2][2]){
#pragma unroll
    for (int n = 0; n < 2; ++n){
      const int row = wc * 64 + (nq + n) * 16 + l15;
      const ushort_t* r = lds + buf * 24576 + 16384 + row * 64;
      br[n][0] = *(const bs8*)(r + ck0);
      br[n][1] = *(const bs8*)(r + ck1);
    }
  };
  auto MMA = [&](int mq, int nq, bs8 (&br)[2][2]){
    __builtin_amdgcn_s_setprio(1);
#pragma unroll
    for (int m = 0; m < 2; ++m)
#pragma unroll
      for (int n = 0; n < 2; ++n){
        acc[mq + m][nq + n] = __builtin_amdgcn_mfma_f32_16x16x32_bf16(aF[m][0], br[n][0], acc[mq + m][nq + n], 0, 0, 0);
        acc[mq + m][nq + n] = __builtin_amdgcn_mfma_f32_16x16x32_bf16(aF[m][1], br[n][1], acc[mq + m][nq + n], 0, 0, 0);
      }
    __builtin_amdgcn_s_setprio(0);
  };

#define BAR() __builtin_amdgcn_s_barrier()
#define LGK() asm volatile("s_waitcnt lgkmcnt(0)" ::: "memory")
#define VMC2() asm volatile("s_waitcnt vmcnt(2)" ::: "memory")

  const int nkt = K >> 6;
  const int nIter = K >> 7;

  STAGE_A(0, 0, 0); STAGE_A(0, 1, 0); STAGE_B(0, 0);
  STAGE_B(1, 1);
  VMC2();
  BAR();

  for (int it = 0; it < nIter; ++it){
    const int kt1 = 2 * it + 1;
    int kt2 = 2 * it + 2; if (kt2 > nkt - 1) kt2 = nkt - 1;
    int kt3 = 2 * it + 3; if (kt3 > nkt - 1) kt3 = nkt - 1;
    RDA(0, 0); RDB(0, 0, bLo);
    STAGE_A(1, 0, kt1);
    BAR(); LGK(); MMA(0, 0, bLo); BAR();
    RDB(0, 2, bHi);
    STAGE_A(1, 1, kt1);
    BAR(); LGK(); MMA(0, 2, bHi); BAR();
    RDA(0, 2);
    STAGE_B(0, kt2);
    BAR(); LGK(); MMA(2, 0, bLo); BAR();
    BAR(); LGK(); MMA(2, 2, bHi);
    VMC2(); BAR();
    RDA(1, 0); RDB(1, 0, bLo);
    STAGE_A(0, 0, kt2);
    BAR(); LGK(); MMA(0, 0, bLo); BAR();
    RDB(1, 2, bHi);
    STAGE_A(0, 1, kt2);
    BAR(); LGK(); MMA(0, 2, bHi); BAR();
    RDA(1, 2);
    STAGE_B(1, kt3);
    BAR(); LGK(); MMA(2, 0, bLo); BAR();
    BAR(); LGK(); MMA(2, 2, bHi);
    VMC2(); BAR();
  }
#undef BAR
#undef LGK
#undef VMC2

#pragma unroll
  for (int m = 0; m < 4; ++m){
    const int r = m0 + wr * 64 + m * 16 + lhi * 4;
#pragma unroll
    for (int n = 0; n < 4; ++n){
      const int c = n0 + wc * 64 + n * 16 + l15;
#pragma unroll
      for (int j = 0; j < 4; ++j)
        C[(size_t)(r + j) * N + c] = acc[m][n][j];
    }
  }
}

// ====== flash attention v7: single-qb blocks, 512 co-resident (2 blocks/CU) ======
// grid (32 bh, 16 y), qb = 15-y (longest first). 8 waves x 16q, QB=128, dbuf K/V.
__global__ __launch_bounds__(512) void attn_kernel(const ushort_t* __restrict__ Qa,
                                                   const ushort_t* __restrict__ Ka,
                                                   const ushort_t* __restrict__ VT,
                                                   ushort_t* __restrict__ O){
  // [K0 12288 | K1 12288 | V0 8192 | V1 8192] elems = 80 KB (2 blocks/CU = 160 KB)
  __shared__ __align__(16) ushort_t lds[40960];
  const int tid = threadIdx.x, lane = tid & 63, wid = tid >> 6;
  const int bh = blockIdx.x;
  const int qb = 15 - blockIdx.y;
  const int b = bh >> 4, h = bh & 15;
  const int qm0 = qb << 7;
  const int nkt = 2 * qb + 2;
  const int l15 = lane & 15, lhi = lane >> 4;

  const ushort_t* Kbh = Ka + (size_t)bh * 2048 * 192;
  const ushort_t* Vbh = VT + (size_t)bh * 128 * 2048;

  const ushort_t* ksrc[3];
#pragma unroll
  for (int i = 0; i < 3; ++i){
    int c = i * 512 + tid;
    int row = c / 24, col = c % 24;
    int hk = (row & 3) | (((row >> 3) & 1) << 2);
    ksrc[i] = Kbh + (size_t)row * 192 + (col ^ hk) * 8;
  }
  const ushort_t* vsrc[2];
#pragma unroll
  for (int i = 0; i < 2; ++i){
    int c = i * 512 + tid;
    int d = c >> 3, col = c & 7;
    vsrc[i] = Vbh + (size_t)d * 2048 + (col ^ (d & 7)) * 8;
  }

  auto STAGE = [&](int kt, int buf){
#pragma unroll
    for (int i = 0; i < 3; ++i)
      gl2lds16(ksrc[i] + (size_t)kt * 12288, lds + buf * 12288 + (i * 512 + tid) * 8);
#pragma unroll
    for (int i = 0; i < 2; ++i)
      gl2lds16(vsrc[i] + kt * 64, lds + 24576 + buf * 8192 + (i * 512 + tid) * 8);
  };

  bs8 qf[6];
  {
    const size_t qrow = ((size_t)bh * 2048 + qm0 + wid * 16 + l15) * 192;
#pragma unroll
    for (int kc = 0; kc < 6; ++kc)
      qf[kc] = *(const bs8*)(Qa + qrow + kc * 32 + lhi * 8);
  }

  f32x4 acc[8] = {};
  float mrow = -1e30f, lrow = 0.f;

  const int mylast = 2 * qb + (wid >> 2);
  const int hkr = (l15 & 3) | (((l15 >> 2) & 1) << 2);

#define BARR() __builtin_amdgcn_s_barrier()
#define LGK0() asm volatile("s_waitcnt lgkmcnt(0)" ::: "memory")
#define VMC(n) asm volatile("s_waitcnt vmcnt(" #n ")" ::: "memory")

  STAGE(0, 0);
  STAGE(1, 1);
  VMC(5);
  BARR();

  for (int kt = 0; kt < nkt; ++kt){
    const int cur = kt & 1;
    const ushort_t* Kb = lds + cur * 12288;
    const ushort_t* Vb = lds + 24576 + cur * 8192;

    if (kt <= mylast){
      f32x4 s[4] = {};
      __builtin_amdgcn_s_setprio(1);
#pragma unroll
      for (int kc = 0; kc < 6; ++kc){
        bs8 kf4[4];
#pragma unroll
        for (int m = 0; m < 4; ++m){
          int row = ((m >> 1) << 5) + ((l15 >> 2) << 3) + ((m & 1) << 2) + (l15 & 3);
          kf4[m] = *(const bs8*)(Kb + row * 192 + (((kc * 4 + lhi) ^ hkr) << 3));
        }
#pragma unroll
        for (int m = 0; m < 4; ++m)
          s[m] = __builtin_amdgcn_mfma_f32_16x16x32_bf16(kf4[m], qf[kc], s[m], 0, 0, 0);
      }
      __builtin_amdgcn_s_setprio(0);

      const bool noMask = (kt * 64 + 63) <= (qm0 + wid * 16);
      const int qi = qm0 + wid * 16 + l15;
      float rmax = -3e38f;
#pragma unroll
      for (int m = 0; m < 4; ++m)
#pragma unroll
        for (int j = 0; j < 4; ++j){
          float sv = s[m][j];
          if (!noMask){
            int ki = kt * 64 + ((m >> 1) << 5) + (lhi << 3) + ((m & 1) << 2) + j;
            if (ki > qi) sv = -3e38f;
          }
          s[m][j] = sv;
          rmax = fmaxf(rmax, sv);
        }
      rmax = fmaxf(rmax, __shfl_xor(rmax, 16));
      rmax = fmaxf(rmax, __shfl_xor(rmax, 32));
      if (!__all(rmax <= mrow + 8.f)){
        float mnew = fmaxf(mrow, rmax);
        float osc = exp2f(mrow - mnew);
        lrow *= osc;
#pragma unroll
        for (int f = 0; f < 8; ++f) acc[f] *= osc;
        mrow = mnew;
      }
      float rsum = 0.f;
#pragma unroll
      for (int m = 0; m < 4; ++m)
#pragma unroll
        for (int j = 0; j < 4; ++j){
          float pv = exp2f(s[m][j] - mrow);
          s[m][j] = pv;
          rsum += pv;
        }
      rsum += __shfl_xor(rsum, 16);
      rsum += __shfl_xor(rsum, 32);
      lrow += rsum;

      bs8 pb[2];
#pragma unroll
      for (int kc2 = 0; kc2 < 2; ++kc2){
        union { bs8 v; unsigned u[4]; } pu;
#pragma unroll
        for (int half = 0; half < 2; ++half){
          const f32x4& sv = s[2 * kc2 + half];
          pu.u[2 * half]     = cvt_pk_bf16(sv[0], sv[1]);
          pu.u[2 * half + 1] = cvt_pk_bf16(sv[2], sv[3]);
        }
        pb[kc2] = pu.v;
      }

      __builtin_amdgcn_s_setprio(1);
#pragma unroll
      for (int kc2 = 0; kc2 < 2; ++kc2)
#pragma unroll
        for (int f = 0; f < 8; ++f){
          bs8 vf = *(const bs8*)(Vb + (f * 16 + l15) * 64 + (((kc2 * 4 + lhi) ^ (l15 & 7)) << 3));
          acc[f] = __builtin_amdgcn_mfma_f32_16x16x32_bf16(vf, pb[kc2], acc[f], 0, 0, 0);
        }
      __builtin_amdgcn_s_setprio(0);
    }

    LGK0();
    BARR();
    if (kt + 2 < nkt){
      STAGE(kt + 2, cur);
      VMC(5);
    } else {
      VMC(0);
    }
    BARR();
  }
#undef BARR
#undef LGK0
#undef VMC

  // epilogue
  {
    float rl = 1.0f / lrow;
    int t = qm0 + wid * 16 + l15;
#pragma unroll
    for (int f = 0; f < 8; ++f){
      u16x4 o;
#pragma unroll
      for (int j = 0; j < 4; ++j) o[j] = f2bf(acc[f][j] * rl);
      *(u16x4*)(O + ((size_t)b * 2048 + t) * 2048 + h * 128 + f * 16 + lhi * 4) = o;
    }
  }
}

extern "C" void kernel_launch(void* const* d_in, const int* in_sizes, int n_in,
                              void* d_out, int out_size, void* d_ws, size_t ws_size,
                              hipStream_t stream){
  constexpr int Bc = 2, Tc = 2048, Cc = 2048, Hc = 16, HDc = 128, RDc = 64, KVRc = 512, QRc = 1024;
  constexpr int Mx = Bc * Tc; // 4096
  const float* x     = (const float*)d_in[0];
  const float* w_dq  = (const float*)d_in[1];
  const float* w_uq  = (const float*)d_in[2];
  const float* w_dkv = (const float*)d_in[3];
  const float* w_uk  = (const float*)d_in[4];
  const float* w_uv  = (const float*)d_in[5];
  const float* w_qr  = (const float*)d_in[6];
  const float* w_kr  = (const float*)d_in[7];
  const float* w_o   = (const float*)d_in[8];
  const float* fc    = (const float*)d_in[9];
  const float* fs    = (const float*)d_in[10];
  float* out = (float*)d_out;

  char* ws = (char*)d_ws;
  size_t off = 0;
  auto alloc = [&](size_t elems) -> ushort_t* {
    ushort_t* p = (ushort_t*)(ws + off);
    off += ((elems * 2) + 255) & ~(size_t)255;
    return p;
  };
  ushort_t* xb    = alloc((size_t)Mx * Cc);
  ushort_t* wdqT  = alloc((size_t)QRc * Cc);
  ushort_t* wdkvT = alloc((size_t)KVRc * Cc);
  ushort_t* wkrT  = alloc((size_t)(Hc * RDc) * Cc);
  ushort_t* wuqT  = alloc((size_t)(Hc * HDc) * QRc);
  ushort_t* wqrT  = alloc((size_t)(Hc * RDc) * QRc);
  ushort_t* wukT  = alloc((size_t)(Hc * HDc) * KVRc);
  ushort_t* wuvT  = alloc((size_t)(Hc * HDc) * KVRc);
  ushort_t* woT   = alloc((size_t)Cc * (Hc * HDc));
  ushort_t* comb1 = alloc((size_t)Mx * 1536);   // [cq 1024 | ckv 512]
  ushort_t* Qa    = alloc((size_t)Bc * Hc * Tc * 192);
  ushort_t* Ka    = alloc((size_t)Bc * Hc * Tc * 192);
  ushort_t* vT    = alloc((size_t)Bc * Hc * HDc * Tc);
  ushort_t* O     = xb;  // alias: xb dead after GEMM1

  cast_x<<<dim3(((size_t)Mx * Cc) / 1024), 256, 0, stream>>>(x, xb);

  tcast_all<<<dim3(14336), 256, 0, stream>>>(w_dq, w_dkv, w_kr, w_uq, w_qr, w_uk, w_uv, w_o,
                                             wdqT, wdkvT, wkrT, wuqT, wqrT, wukT, wuvT, woT);

  // GEMM1: x @ [w_dq|w_dkv|w_kr] -> comb1[.][1536] + rope(kr)->Ka[..][128..192)
  gemm256<1, ushort_t><<<dim3((Mx / 256) * (2560 / 256)), 512, 0, stream>>>(
      xb, Cc, wdqT, comb1, Mx, 2560, Cc, Ka, fc, fs);
  // GEMM2+3 fused: cq @ [w_uq|w_qr] -> Qa ; ckv @ [w_uk|w_uv] -> Ka(kc) + vT (transposed)
  gemm23<<<dim3(448), 512, 0, stream>>>(comb1, wuqT, comb1 + QRc, wukT, vT, Qa, Ka, fc, fs);

  attn_kernel<<<dim3(Bc * Hc, 16), 512, 0, stream>>>(Qa, Ka, vT, O);

  // GEMM4: O @ w_o -> out [4096][2048] fp32, 256x128 tiles = 256 blocks (full fill)
  gemm4_128<<<dim3(256), 512, 0, stream>>>(O, Hc * HDc, woT, out, Mx, Cc, Hc * HDc);
}